// Round 3
// baseline (15867.328 us; speedup 1.0000x reference)
//
#include <hip/hip_runtime.h>

// ---------------------------------------------------------------------------
// MultilayerGRU: B=32, S=4096, H=256, O=256, L=2
// Round 8: LDS-bandwidth diet. Round 7 was LDS-BW-bound (~298KB/step/WG;
// Wg-in-LDS re-read 128KB of static weights every step). Reverse trade:
//   - ALL gate weights in registers (192 VGPR/wave, 2 nt-tiles x 3 gates)
//   - x-side moved to LDS: XL[2][3][4096] double-buffer via global_load_lds
//     (wave-private slabs, 1-step-ahead prefetch, vmcnt(0) folded into the
//     end-of-step barrier where the loads are a full step old)
//   - x added AFTER the MFMA loop (acc init 0) so JIT x-reads hide under MFMA
// LDS 144KB -> 64KB/WG; per-step LDS traffic ~298KB -> ~170KB.
// gemm3 identical to round 7.
// ---------------------------------------------------------------------------

typedef __attribute__((ext_vector_type(8))) short short8;
typedef __attribute__((ext_vector_type(4))) float f32x4;

#define TC      256
#define NCHUNK  16
#define SSZ     4096
#define LW      (256*256)

#define SIGSC  (-1.44269504089f)   // -log2(e): sigmoid(x) = rcp(1+exp2(-log2e*x))
#define TANHSC ( 2.88539008178f)   // 2*log2(e): tanh(x) = 1 - 2*rcp(exp2(2log2e*x)+1)

__device__ __forceinline__ float bf2f(unsigned short u) {
    union { unsigned int i; float f; } v; v.i = ((unsigned int)u) << 16; return v.f;
}
__device__ __forceinline__ unsigned short f2bf(float f) {        // RNE
    union { float f; unsigned int i; } v; v.f = f;
    v.i += 0x7fff + ((v.i >> 16) & 1);
    return (unsigned short)(v.i >> 16);
}
__device__ __forceinline__ unsigned int pkbf(float lo, float hi) {
    union { float f; unsigned int i; } a, b; a.f = lo; b.f = hi;
    return __builtin_amdgcn_perm(b.i + 0x8000u, a.i + 0x8000u, 0x07060302);
}
__device__ __forceinline__ short8 cvt8s(const float* p, float s) {
    float4 a = *(const float4*)p;
    float4 b = *(const float4*)(p + 4);
    short8 r;
    r[0] = (short)f2bf(a.x * s); r[1] = (short)f2bf(a.y * s);
    r[2] = (short)f2bf(a.z * s); r[3] = (short)f2bf(a.w * s);
    r[4] = (short)f2bf(b.x * s); r[5] = (short)f2bf(b.y * s);
    r[6] = (short)f2bf(b.z * s); r[7] = (short)f2bf(b.w * s);
    return r;
}
// LDS-only barrier (mid-step: no vm dependency crosses it).
__device__ __forceinline__ void wg_barrier() {
    asm volatile("s_waitcnt lgkmcnt(0)" ::: "memory");
    __builtin_amdgcn_s_barrier();
}
// async global->LDS, 16 B per lane; LDS dest = wave-uniform base + lane*16
__device__ __forceinline__ void gl_lds16(const unsigned short* g, unsigned short* l) {
    __builtin_amdgcn_global_load_lds(
        (const __attribute__((address_space(1))) unsigned int*)g,
        (__attribute__((address_space(3))) unsigned int*)l,
        16, 0, 0);
}

// ---------------------------------------------------------------------------
// Fused GEMM dispatch, role by blockIdx.y (IDENTICAL to round 7):
//   jt  0..11 : XS0(c)   = x-side layer 0, chunk c        (c <= 15)
//   jt 12..23 : XS1(c-1) = x-side layer 1 from Hc0        (1 <= c <= 16)
//   jt 24..27 : y(c-2)   = output projection from Hc1     (c >= 2)
// XS layout (per t, wgs): 3 gate-planes x 4096 shorts; scan thread stid owns
// shorts [stid*8 .. stid*8+7] of each plane.
// ---------------------------------------------------------------------------
__global__ __launch_bounds__(256, 2) void gemm3(
    const float* __restrict__ x,
    const unsigned short* __restrict__ Hc0, const unsigned short* __restrict__ Hc1,
    const float* __restrict__ Wxz, const float* __restrict__ Wxr, const float* __restrict__ Wxg,
    const float* __restrict__ bz,  const float* __restrict__ br,  const float* __restrict__ bg,
    const float* __restrict__ Why, const float* __restrict__ by,
    unsigned short* __restrict__ XS0, unsigned short* __restrict__ XS1,
    float* __restrict__ out, int c)
{
    __shared__ unsigned short Alds[64 * 256];
    __shared__ unsigned short Wlds[64 * 256];

    const int jt = blockIdx.y;
    const void* Aptr; int a_mode, c0abs = 0, o_mode, jtl;
    const float *w0, *w1, *w2, *b0, *b1, *b2; void* Optr;
    if (jt < 12) {
        if (c > 15) return;
        Aptr = x; a_mode = 0; c0abs = c * TC;
        w0 = Wxz; w1 = Wxr; w2 = Wxg; b0 = bz; b1 = br; b2 = bg;
        Optr = XS0; o_mode = 0; jtl = jt;
    } else if (jt < 24) {
        if (c < 1 || c > 16) return;
        Aptr = Hc0; a_mode = 1;
        w0 = Wxz + LW; w1 = Wxr + LW; w2 = Wxg + LW;
        b0 = bz + 256; b1 = br + 256; b2 = bg + 256;
        Optr = XS1; o_mode = 0; jtl = jt - 12;
    } else {
        if (c < 2) return;
        Aptr = Hc1; a_mode = 1; c0abs = (c - 2) * TC;
        w0 = Why; w1 = Why; w2 = Why; b0 = by; b1 = by; b2 = by;
        Optr = out; o_mode = 1; jtl = jt - 24;
    }

    const int tid = threadIdx.x;
    const int mt = blockIdx.x;

    for (int idx = tid; idx < 4096; idx += 256) {
        int row = idx >> 6;
        int kq  = (idx & 63) << 2;
        int sw  = row * 256 + (((((kq >> 3) ^ (row & 7)) << 3)) | (kq & 7));
        if (a_mode == 0) {
            int i = mt * 64 + row; int tc = i >> 5, b = i & 31;
            const float* p = (const float*)Aptr + ((size_t)b * SSZ + (size_t)(c0abs + tc)) * 256 + kq;
            float4 v = *(const float4*)p;
            ushort4 u; u.x = f2bf(v.x); u.y = f2bf(v.y); u.z = f2bf(v.z); u.w = f2bf(v.w);
            *(ushort4*)&Alds[sw] = u;
        } else {
            const unsigned short* p = (const unsigned short*)Aptr + (size_t)(mt * 64 + row) * 256 + kq;
            *(ushort4*)&Alds[sw] = *(const ushort4*)p;
        }
    }
    for (int idx = tid; idx < 4096; idx += 256) {
        int row = idx >> 6;
        int kq  = (idx & 63) << 2;
        int j   = jtl * 64 + row;
        const float* wp = (j < 256) ? w0 : ((j < 512) ? w1 : w2);
        const float* p  = wp + (size_t)(j & 255) * 256 + kq;
        float4 v = *(const float4*)p;
        ushort4 u; u.x = f2bf(v.x); u.y = f2bf(v.y); u.z = f2bf(v.z); u.w = f2bf(v.w);
        int sw = row * 256 + (((((kq >> 3) ^ (row & 7)) << 3)) | (kq & 7));
        *(ushort4*)&Wlds[sw] = u;
    }
    __syncthreads();

    const int lane = tid & 63, wv = tid >> 6;
    const int cl = lane & 15, qr = lane >> 4;
    f32x4 acc[4];
    #pragma unroll
    for (int nt = 0; nt < 4; ++nt) acc[nt] = (f32x4){0.f, 0.f, 0.f, 0.f};

    #pragma unroll
    for (int kt = 0; kt < 8; ++kt) {
        int kb = kt * 4 + qr;
        short8 af = *(const short8*)&Alds[(wv * 16 + cl) * 256 + ((kb ^ (cl & 7)) << 3)];
        #pragma unroll
        for (int nt = 0; nt < 4; ++nt) {
            short8 bf = *(const short8*)&Wlds[(nt * 16 + cl) * 256 + ((kb ^ (cl & 7)) << 3)];
            acc[nt] = __builtin_amdgcn_mfma_f32_16x16x32_bf16(af, bf, acc[nt], 0, 0, 0);
        }
    }

    #pragma unroll
    for (int nt = 0; nt < 4; ++nt) {
        int j = jtl * 64 + nt * 16 + cl;
        const float* bp = (j < 256) ? b0 : ((j < 512) ? b1 : b2);
        float bias = bp[j & 255];
        #pragma unroll
        for (int r = 0; r < 4; ++r) {
            float v = acc[nt][r] + bias;
            int m = mt * 64 + wv * 16 + qr * 4 + r;      // C/D: row=(lane>>4)*4+reg, col=lane&15
            if (o_mode == 0) {
                int t = m >> 5, b = m & 31;
                int wgs = b >> 4, scl = b & 15;          // scan: sample -> lane cl
                int gate = j >> 8, cc = j & 255;
                // scan thread (8 waves): n = swv*32 + snt*16 + sqr*4 + sr
                int swv = cc >> 5, snt = (cc >> 4) & 1, sqr = (cc >> 2) & 3, sr = cc & 3;
                int stid = swv * 64 + sqr * 16 + scl;
                size_t off = (((size_t)((t * 2 + wgs) * 3 + gate)) << 12)
                           + (size_t)stid * 8 + (snt * 4 + sr);
                float gs = (gate < 2) ? SIGSC : TANHSC;
                ((unsigned short*)Optr)[off] = f2bf(v * gs);
            } else {
                int tc = m >> 5, b = m & 31;
                ((float*)Optr)[(size_t)b * (SSZ * 256) + (size_t)(c0abs + tc) * 256 + j] = v;
            }
        }
    }
}

// ---------------------------------------------------------------------------
// Dual-layer GRU scan: blockIdx 0,1 -> layer 0 chunk c; 2,3 -> layer 1 chunk
// c-1. 512 threads = 8 waves (2/SIMD), each wave owns 2 nt-tiles (32 n).
// ALL gate weights in registers (192 VGPR). x-side in LDS (XL dbuf via
// global_load_lds, wave-private slabs). 2 barriers/step; only the end-of-step
// barrier drains vmcnt (prefetch is a full step old there).
// ---------------------------------------------------------------------------
__global__ __launch_bounds__(512, 2) void scan_dual(
    const unsigned short* __restrict__ XS0, const unsigned short* __restrict__ XS1,
    unsigned short* __restrict__ Hc0, unsigned short* __restrict__ Hc1,
    float* __restrict__ hstate,                // ws [2][32][256] fp32
    const float* __restrict__ hidden_in,       // d_in[1] [32][2][256] fp32
    const float* __restrict__ Whz0, const float* __restrict__ Whr0,
    const float* __restrict__ Whg0,
    int c, float* __restrict__ dout_tail)      // d_out + B*S*O, [32][2][256]
{
    __shared__ unsigned short hA[4096];        // h   [b:16][n:256] bf16, swizzled
    __shared__ unsigned short A2[4096];        // h*r [b:16][n:256]
    __shared__ unsigned short XL[2][3][4096];  // x-side double buffer, 48 KiB

    const int layer = blockIdx.x >> 1;
    const int wg    = blockIdx.x & 1;
    const int chunk = (layer == 0) ? c : c - 1;
    if (chunk < 0 || chunk > 15) return;

    const unsigned short* XS = (layer == 0) ? XS0 : XS1;
    unsigned short* Hout     = (layer == 0) ? Hc0 : Hc1;
    const float* Whz = Whz0 + (size_t)layer * LW;
    const float* Whr = Whr0 + (size_t)layer * LW;
    const float* Whg = Whg0 + (size_t)layer * LW;
    const int first_chunk = (chunk == 0), last_chunk = (chunk == NCHUNK - 1);

    const int tid  = threadIdx.x;
    const int lane = tid & 63, wv = tid >> 6;  // 8 waves
    const int cl   = lane & 15, qr = lane >> 4;
    const int swl  = cl & 7;
    const int b    = wg * 16 + cl;             // this lane's sample

    // prologue prefetch of x(t=0) into XL[0] (own wave slab)
    const unsigned short* xsg = XS + (size_t)wg * 12288 + (size_t)tid * 8;
    gl_lds16(xsg,        &XL[0][0][wv * 512]);
    gl_lds16(xsg + 4096, &XL[0][1][wv * 512]);
    gl_lds16(xsg + 8192, &XL[0][2][wv * 512]);

    // ---- ALL weights as register A-frags (pre-scaled) ----
    short8 wzf[2][8], wrf[2][8], wgf[2][8];
    #pragma unroll
    for (int nt = 0; nt < 2; ++nt) {
        int n = wv * 32 + nt * 16 + cl;
        #pragma unroll
        for (int kt = 0; kt < 8; ++kt) {
            int k0 = kt * 32 + qr * 8;
            wzf[nt][kt] = cvt8s(Whz + (size_t)n * 256 + k0, SIGSC);
            wrf[nt][kt] = cvt8s(Whr + (size_t)n * 256 + k0, SIGSC);
            wgf[nt][kt] = cvt8s(Whg + (size_t)n * 256 + k0, TANHSC);
        }
    }

    // per-nt invariant packed-write offsets: 4 consecutive n
    int wro[2];
    #pragma unroll
    for (int nt = 0; nt < 2; ++nt) {
        int nb = wv * 32 + nt * 16 + qr * 4;
        wro[nt] = cl * 256 + ((((nb >> 3) ^ swl) << 3) | (nb & 4));
    }

    // h master: lane holds h[b][nb..nb+3] per tile (fp32), init hA image
    float hreg[2][4];
    #pragma unroll
    for (int nt = 0; nt < 2; ++nt) {
        int nb = wv * 32 + nt * 16 + qr * 4;
        float4 h4;
        if (first_chunk) h4 = *(const float4*)(hidden_in + (size_t)b * 512 + layer * 256 + nb);
        else             h4 = *(const float4*)(hstate + layer * 8192 + b * 256 + nb);
        hreg[nt][0] = h4.x; hreg[nt][1] = h4.y; hreg[nt][2] = h4.z; hreg[nt][3] = h4.w;
        uint2 p; p.x = pkbf(h4.x, h4.y); p.y = pkbf(h4.z, h4.w);
        *(uint2*)&hA[wro[nt]] = p;
    }

    // drain XL[0] prefetch + hA init, then go
    asm volatile("s_waitcnt vmcnt(0) lgkmcnt(0)" ::: "memory");
    __builtin_amdgcn_s_barrier();

    uint2 hpk[2];   // packed h(t) held across barrier B for the Hout store
    const size_t holane = (size_t)(wg * 16 + cl) * 256 + (size_t)wv * 32 + (size_t)qr * 4;

    #pragma unroll 1
    for (int t = 0; t < TC; ++t) {
        const int cur = t & 1, nxt = cur ^ 1;

        // Hout(t-1): direct store from registers, off the critical path
        if (t) {
            unsigned short* hp = Hout + (size_t)(t - 1) * 8192 + holane;
            *(uint2*)hp        = hpk[0];
            *(uint2*)(hp + 16) = hpk[1];
        }

        // prefetch x(t+1) into XL[nxt] (own wave slab; drained at barrier B)
        const unsigned short* gnx = xsg + ((t + 1 < TC) ? 24576 : 0);
        gl_lds16(gnx,        &XL[nxt][0][wv * 512]);
        gl_lds16(gnx + 4096, &XL[nxt][1][wv * 512]);
        gl_lds16(gnx + 8192, &XL[nxt][2][wv * 512]);
        xsg = gnx;

        // JIT x-reads for this step (LDS, transient regs)
        const unsigned short* xb = &XL[cur][0][tid * 8];
        short8 xz8 = *(const short8*)xb;
        short8 xr8 = *(const short8*)(xb + 4096);

        // pass 1: z, r  (acc = 0; x added after the MFMA loop)
        f32x4 az[2], ar[2];
        #pragma unroll
        for (int nt = 0; nt < 2; ++nt) { az[nt] = (f32x4){0.f,0.f,0.f,0.f}; ar[nt] = az[nt]; }
        #pragma unroll
        for (int kt = 0; kt < 8; ++kt) {
            int kb = kt * 4 + qr;
            short8 bf = *(const short8*)&hA[cl * 256 + ((kb ^ swl) << 3)];
            az[0] = __builtin_amdgcn_mfma_f32_16x16x32_bf16(wzf[0][kt], bf, az[0], 0, 0, 0);
            ar[0] = __builtin_amdgcn_mfma_f32_16x16x32_bf16(wrf[0][kt], bf, ar[0], 0, 0, 0);
            az[1] = __builtin_amdgcn_mfma_f32_16x16x32_bf16(wzf[1][kt], bf, az[1], 0, 0, 0);
            ar[1] = __builtin_amdgcn_mfma_f32_16x16x32_bf16(wrf[1][kt], bf, ar[1], 0, 0, 0);
        }

        float zs[2][4];
        #pragma unroll
        for (int nt = 0; nt < 2; ++nt) {
            float a2v[4];
            #pragma unroll
            for (int r = 0; r < 4; ++r) {
                int e = nt * 4 + r;
                float sz = az[nt][r] + bf2f((unsigned short)xz8[e]);
                zs[nt][r] = __builtin_amdgcn_rcpf(1.0f + __builtin_amdgcn_exp2f(sz));
                float sr = ar[nt][r] + bf2f((unsigned short)xr8[e]);
                float rr = __builtin_amdgcn_rcpf(1.0f + __builtin_amdgcn_exp2f(sr));
                a2v[r] = rr * hreg[nt][r];
            }
            uint2 p; p.x = pkbf(a2v[0], a2v[1]); p.y = pkbf(a2v[2], a2v[3]);
            *(uint2*)&A2[wro[nt]] = p;
        }
        wg_barrier();

        // pass 2: g = (h*r) @ Whg^T  (weights in regs, B from A2)
        short8 xg8 = *(const short8*)(xb + 8192);
        f32x4 ag[2];
        #pragma unroll
        for (int nt = 0; nt < 2; ++nt) ag[nt] = (f32x4){0.f,0.f,0.f,0.f};
        #pragma unroll
        for (int kt = 0; kt < 8; ++kt) {
            int kb = kt * 4 + qr;
            short8 bf = *(const short8*)&A2[cl * 256 + ((kb ^ swl) << 3)];
            ag[0] = __builtin_amdgcn_mfma_f32_16x16x32_bf16(wgf[0][kt], bf, ag[0], 0, 0, 0);
            ag[1] = __builtin_amdgcn_mfma_f32_16x16x32_bf16(wgf[1][kt], bf, ag[1], 0, 0, 0);
        }
        #pragma unroll
        for (int nt = 0; nt < 2; ++nt) {
            float hn4[4];
            #pragma unroll
            for (int r = 0; r < 4; ++r) {
                int e = nt * 4 + r;
                float sg = ag[nt][r] + bf2f((unsigned short)xg8[e]);
                float g = 1.0f - 2.0f * __builtin_amdgcn_rcpf(
                              1.0f + __builtin_amdgcn_exp2f(sg));
                float hn = g + zs[nt][r] * (hreg[nt][r] - g);
                hreg[nt][r] = hn;
                hn4[r] = hn;
            }
            uint2 p; p.x = pkbf(hn4[0], hn4[1]); p.y = pkbf(hn4[2], hn4[3]);
            hpk[nt] = p;
            *(uint2*)&hA[wro[nt]] = p;
        }
        // barrier B: hA(t) visible + XL prefetch (a full step old) drained
        asm volatile("s_waitcnt vmcnt(0) lgkmcnt(0)" ::: "memory");
        __builtin_amdgcn_s_barrier();
    }

    // tail: Hout(TC-1), persist state, emit final hidden on last chunk
    {
        unsigned short* hp = Hout + (size_t)(TC - 1) * 8192 + holane;
        *(uint2*)hp        = hpk[0];
        *(uint2*)(hp + 16) = hpk[1];
    }
    #pragma unroll
    for (int nt = 0; nt < 2; ++nt) {
        int nb = wv * 32 + nt * 16 + qr * 4;
        float4 h4; h4.x = hreg[nt][0]; h4.y = hreg[nt][1]; h4.z = hreg[nt][2]; h4.w = hreg[nt][3];
        *(float4*)(hstate + layer * 8192 + b * 256 + nb) = h4;
        if (last_chunk)
            *(float4*)(dout_tail + (size_t)b * 512 + layer * 256 + nb) = h4;
    }
}

extern "C" void kernel_launch(void* const* d_in, const int* in_sizes, int n_in,
                              void* d_out, int out_size, void* d_ws, size_t ws_size,
                              hipStream_t stream) {
    const float* x   = (const float*)d_in[0];
    const float* h0  = (const float*)d_in[1];
    const float* Wxz = (const float*)d_in[2];
    const float* Whz = (const float*)d_in[3];
    const float* bz  = (const float*)d_in[4];
    const float* Wxr = (const float*)d_in[5];
    const float* Whr = (const float*)d_in[6];
    const float* br  = (const float*)d_in[7];
    const float* Wxg = (const float*)d_in[8];
    const float* Whg = (const float*)d_in[9];
    const float* bg  = (const float*)d_in[10];
    const float* Why = (const float*)d_in[11];
    const float* by  = (const float*)d_in[12];
    float* out = (float*)d_out;

    char* ws = (char*)d_ws;
    unsigned short* bufA = (unsigned short*)(ws);                    // XS0 12,582,912 B
    unsigned short* bufB = (unsigned short*)(ws + 12582912);         // XS1 12,582,912 B
    unsigned short* Hc0  = (unsigned short*)(ws + 25165824);         //  4,194,304 B
    unsigned short* Hc1  = (unsigned short*)(ws + 29360128);         //  4,194,304 B
    float*          hst  = (float*)(ws + 33554432);                  //     65,536 B
    float* dout_tail = out + (size_t)32 * 4096 * 256;

    // chunk-pipelined: iter i computes XS0(i), XS1(i-1), y(i-2) in one gemm
    // dispatch, then scans layer0(i) + layer1(i-1) concurrently.
    for (int i = 0; i <= 17; ++i) {
        gemm3<<<dim3(128, 28), 256, 0, stream>>>(x, Hc0, Hc1,
                                                 Wxz, Wxr, Wxg, bz, br, bg,
                                                 Why, by, bufA, bufB, out, i);
        if (i <= 16)
            scan_dual<<<4, 512, 0, stream>>>(bufA, bufB, Hc0, Hc1, hst, h0,
                                             Whz, Whr, Whg, i, dout_tail);
    }
}

// Round 4
// 7978.373 us; speedup vs baseline: 1.9888x; 1.9888x over previous
//
#include <hip/hip_runtime.h>

// ---------------------------------------------------------------------------
// MultilayerGRU: B=32, S=4096, H=256, O=256, L=2
// Round 9: single fused dispatch per pipeline iteration.
//   - Round-8 post-mortem: >128 arch-VGPR demand => AGPR shuttling (~2x VALU
//     tax, VGPR_Count pinned at 128). Scan body reverted to round-7 shape
//     (z/r weights in regs = 128 VGPR, g weights in LDS).
//   - gemm WGs merged INTO the scan dispatch: bids 0-3 = scan (layer0 chunk i,
//     layer1 chunk i-2), bids 4.. = gemm XS0(i+1) | XS1(i-1) | y(i-3) running
//     on the ~252 idle CUs. All dependencies cross dispatch boundaries;
//     intra-dispatch hazards removed by parity double-buffering.
//   - TC=128 / NCHUNK=32 so the parity-doubled buffers fit the EXACT same
//     33.6MB workspace layout as before.
//   - Wg LDS frags in per-wave LINEAR layout: conflict-free ds_read_b128,
//     zero swizzle math on the pass-2 critical path.
// ---------------------------------------------------------------------------

typedef __attribute__((ext_vector_type(8))) short short8;
typedef __attribute__((ext_vector_type(4))) float f32x4;

#define TC      128
#define NCHUNK  32
#define SSZ     4096
#define LW      (256*256)
#define XSPAR   3145728   // shorts per parity: TC*2*3*4096
#define HPAR    1048576   // shorts per parity: TC*32*256

#define SIGSC  (-1.44269504089f)   // -log2(e): sigmoid(x) = rcp(1+exp2(-log2e*x))
#define TANHSC ( 2.88539008178f)   // 2*log2(e): tanh(x) = 1 - 2*rcp(exp2(2log2e*x)+1)

__device__ __forceinline__ float bf2f(unsigned short u) {
    union { unsigned int i; float f; } v; v.i = ((unsigned int)u) << 16; return v.f;
}
__device__ __forceinline__ unsigned short f2bf(float f) {        // RNE
    union { float f; unsigned int i; } v; v.f = f;
    v.i += 0x7fff + ((v.i >> 16) & 1);
    return (unsigned short)(v.i >> 16);
}
__device__ __forceinline__ unsigned int pkbf(float lo, float hi) {
    union { float f; unsigned int i; } a, b; a.f = lo; b.f = hi;
    return __builtin_amdgcn_perm(b.i + 0x8000u, a.i + 0x8000u, 0x07060302);
}
__device__ __forceinline__ short8 cvt8s(const float* p, float s) {
    float4 a = *(const float4*)p;
    float4 b = *(const float4*)(p + 4);
    short8 r;
    r[0] = (short)f2bf(a.x * s); r[1] = (short)f2bf(a.y * s);
    r[2] = (short)f2bf(a.z * s); r[3] = (short)f2bf(a.w * s);
    r[4] = (short)f2bf(b.x * s); r[5] = (short)f2bf(b.y * s);
    r[6] = (short)f2bf(b.z * s); r[7] = (short)f2bf(b.w * s);
    return r;
}
__device__ __forceinline__ void wg_barrier() {
    asm volatile("s_waitcnt lgkmcnt(0)" ::: "memory");
    __builtin_amdgcn_s_barrier();
}

struct ScanS {                       // 147456 B
    unsigned short hA[4096];         // h   [b:16][n:256] bf16, swizzled
    unsigned short A2[4096];         // h*r [b:16][n:256]
    unsigned short WgL[65536];       // Whg frags, per-wave LINEAR layout
};
struct GemmS {                       // 98304 B
    unsigned short Alds[128 * 256];
    unsigned short Wlds[64 * 256];
};

// ---------------------------------------------------------------------------
// One dispatch per pipeline iteration i:
//   bid 0,1   : scan layer 0, chunk i,   wg = bid
//   bid 2,3   : scan layer 1, chunk i-2, wg = bid-2
//   bid 4-387 : gemm XS0(i+1)  [A = x fp32]
//   bid 388-771: gemm XS1(i-1) [A = Hc0 bf16, from dispatch i-1's scan]
//   bid 772-899: gemm y(i-3)   [A = Hc1 bf16]
// All XS0/XS1/Hc0/Hc1 are parity (chunk&1) double-buffered -> no intra-
// dispatch read/write overlap; every producer->consumer edge crosses a
// dispatch boundary (stream-serial).
// ---------------------------------------------------------------------------
__global__ __launch_bounds__(512, 2) void fused(
    const float* __restrict__ x, const float* __restrict__ h0,
    const float* __restrict__ Wxz, const float* __restrict__ Whz, const float* __restrict__ bz,
    const float* __restrict__ Wxr, const float* __restrict__ Whr, const float* __restrict__ br,
    const float* __restrict__ Wxg, const float* __restrict__ Whg, const float* __restrict__ bg,
    const float* __restrict__ Why, const float* __restrict__ by,
    unsigned short* __restrict__ XS0b, unsigned short* __restrict__ XS1b,
    unsigned short* __restrict__ Hc0b, unsigned short* __restrict__ Hc1b,
    float* __restrict__ hst, float* __restrict__ out,
    float* __restrict__ dout_tail, int i)
{
    __shared__ union { ScanS s; GemmS g; } sm;

    const int bid = blockIdx.x;
    const int tid = threadIdx.x;

    if (bid < 4) {
        // =================== SCAN ROLE (round-7 body, TC=128) ===================
        const int layer = bid >> 1;
        const int wg    = bid & 1;
        const int chunk = (layer == 0) ? i : i - 2;
        if ((unsigned)chunk > 31u) return;

        const unsigned short* XS = ((layer == 0) ? XS0b : XS1b) + (size_t)(chunk & 1) * XSPAR;
        unsigned short* Hout     = ((layer == 0) ? Hc0b : Hc1b) + (size_t)(chunk & 1) * HPAR;
        const float* Whz_l = Whz + (size_t)layer * LW;
        const float* Whr_l = Whr + (size_t)layer * LW;
        const float* Whg_l = Whg + (size_t)layer * LW;
        const int first_chunk = (chunk == 0), last_chunk = (chunk == NCHUNK - 1);

        unsigned short* hA  = sm.s.hA;
        unsigned short* A2  = sm.s.A2;
        unsigned short* WgL = sm.s.WgL;

        const int lane = tid & 63, wv = tid >> 6;  // 8 waves
        const int cl   = lane & 15, qr = lane >> 4;
        const int swl  = cl & 7;
        const int b    = wg * 16 + cl;             // this lane's sample

        // ---- stage Whg into LDS, per-wave LINEAR frag layout ----
        // dest idx = ((wvv*2+nt)*8+kt)*64 + lane_s; 16B per slot.
        for (int idx = tid; idx < 8192; idx += 512) {
            int lane_s = idx & 63, kt = (idx >> 6) & 7, ntv = (idx >> 9) & 1, wvv = idx >> 10;
            int n  = wvv * 32 + ntv * 16 + (lane_s & 15);
            int k0 = kt * 32 + (lane_s >> 4) * 8;
            short8 f = cvt8s(Whg_l + (size_t)n * 256 + k0, TANHSC);
            *(short8*)&WgL[(size_t)idx * 8] = f;
        }

        // ---- z/r weights as register A-frags (128 VGPR, the proven cap) ----
        short8 wzf[2][8], wrf[2][8];
        #pragma unroll
        for (int nt = 0; nt < 2; ++nt) {
            int n = wv * 32 + nt * 16 + cl;
            #pragma unroll
            for (int kt = 0; kt < 8; ++kt) {
                int k0 = kt * 32 + qr * 8;
                wzf[nt][kt] = cvt8s(Whz_l + (size_t)n * 256 + k0, SIGSC);
                wrf[nt][kt] = cvt8s(Whr_l + (size_t)n * 256 + k0, SIGSC);
            }
        }

        // per-nt invariant packed-write offsets: 4 consecutive n
        int wro[2];
        #pragma unroll
        for (int nt = 0; nt < 2; ++nt) {
            int nb = wv * 32 + nt * 16 + qr * 4;
            wro[nt] = cl * 256 + ((((nb >> 3) ^ swl) << 3) | (nb & 4));
        }

        // h master: lane holds h[b][nb..nb+3] per tile (fp32), init hA image
        float hreg[2][4];
        #pragma unroll
        for (int nt = 0; nt < 2; ++nt) {
            int nb = wv * 32 + nt * 16 + qr * 4;
            float4 h4;
            if (first_chunk) h4 = *(const float4*)(h0 + (size_t)b * 512 + layer * 256 + nb);
            else             h4 = *(const float4*)(hst + layer * 8192 + b * 256 + nb);
            hreg[nt][0] = h4.x; hreg[nt][1] = h4.y; hreg[nt][2] = h4.z; hreg[nt][3] = h4.w;
            uint2 p; p.x = pkbf(h4.x, h4.y); p.y = pkbf(h4.z, h4.w);
            *(uint2*)&hA[wro[nt]] = p;
        }

        // x-side: per-lane pointer; per-t stride = 2 wgs * 3 * 4096 = 24576
        const unsigned short* xp = XS + (size_t)wg * 12288 + (size_t)tid * 8;
        short8 xz = *(const short8*)(xp);
        short8 xr = *(const short8*)(xp + 4096);
        short8 xg = *(const short8*)(xp + 8192);

        wg_barrier();   // hA init + WgL fill visible

        uint2 hpk[2];
        const size_t holane = (size_t)(wg * 16 + cl) * 256 + (size_t)wv * 32 + (size_t)qr * 4;

        #pragma unroll 1
        for (int t = 0; t < TC; ++t) {
            // Hout(t-1): store from registers, off the critical path
            if (t) {
                unsigned short* hp = Hout + (size_t)(t - 1) * 8192 + holane;
                *(uint2*)hp        = hpk[0];
                *(uint2*)(hp + 16) = hpk[1];
            }

            // prefetch x(t+1)
            const unsigned short* xq = xp + (size_t)((t + 1 < TC) ? t + 1 : t) * 24576;
            short8 nz = *(const short8*)(xq);
            short8 nr = *(const short8*)(xq + 4096);
            short8 ng = *(const short8*)(xq + 8192);

            // pass 1: z, r
            f32x4 az[2], ar[2];
            #pragma unroll
            for (int nt = 0; nt < 2; ++nt) {
                #pragma unroll
                for (int r = 0; r < 4; ++r) {
                    az[nt][r] = bf2f((unsigned short)xz[nt * 4 + r]);
                    ar[nt][r] = bf2f((unsigned short)xr[nt * 4 + r]);
                }
            }
            #pragma unroll
            for (int kt = 0; kt < 8; ++kt) {
                int kb = kt * 4 + qr;
                short8 bf = *(const short8*)&hA[cl * 256 + ((kb ^ swl) << 3)];
                az[0] = __builtin_amdgcn_mfma_f32_16x16x32_bf16(wzf[0][kt], bf, az[0], 0, 0, 0);
                ar[0] = __builtin_amdgcn_mfma_f32_16x16x32_bf16(wrf[0][kt], bf, ar[0], 0, 0, 0);
                az[1] = __builtin_amdgcn_mfma_f32_16x16x32_bf16(wzf[1][kt], bf, az[1], 0, 0, 0);
                ar[1] = __builtin_amdgcn_mfma_f32_16x16x32_bf16(wrf[1][kt], bf, ar[1], 0, 0, 0);
            }

            float zs[2][4];
            #pragma unroll
            for (int nt = 0; nt < 2; ++nt) {
                float a2v[4];
                #pragma unroll
                for (int r = 0; r < 4; ++r) {
                    zs[nt][r] = __builtin_amdgcn_rcpf(1.0f + __builtin_amdgcn_exp2f(az[nt][r]));
                    float rr  = __builtin_amdgcn_rcpf(1.0f + __builtin_amdgcn_exp2f(ar[nt][r]));
                    a2v[r] = rr * hreg[nt][r];
                }
                uint2 p; p.x = pkbf(a2v[0], a2v[1]); p.y = pkbf(a2v[2], a2v[3]);
                *(uint2*)&A2[wro[nt]] = p;
            }
            wg_barrier();

            // pass 2: g = (h*r) @ Whg^T  (A from LINEAR WgL: conflict-free)
            f32x4 ag[2];
            #pragma unroll
            for (int nt = 0; nt < 2; ++nt) {
                #pragma unroll
                for (int r = 0; r < 4; ++r)
                    ag[nt][r] = bf2f((unsigned short)xg[nt * 4 + r]);
            }
            #pragma unroll
            for (int kt = 0; kt < 8; ++kt) {
                int kb = kt * 4 + qr;
                int ko = (wv * 16 + kt) * 512 + lane * 8;
                short8 bf  = *(const short8*)&A2[cl * 256 + ((kb ^ swl) << 3)];
                short8 af0 = *(const short8*)&WgL[ko];
                short8 af1 = *(const short8*)&WgL[ko + 4096];
                ag[0] = __builtin_amdgcn_mfma_f32_16x16x32_bf16(af0, bf, ag[0], 0, 0, 0);
                ag[1] = __builtin_amdgcn_mfma_f32_16x16x32_bf16(af1, bf, ag[1], 0, 0, 0);
            }
            #pragma unroll
            for (int nt = 0; nt < 2; ++nt) {
                float hn4[4];
                #pragma unroll
                for (int r = 0; r < 4; ++r) {
                    float g = 1.0f - 2.0f * __builtin_amdgcn_rcpf(
                                  1.0f + __builtin_amdgcn_exp2f(ag[nt][r]));
                    float hn = g + zs[nt][r] * (hreg[nt][r] - g);
                    hreg[nt][r] = hn;
                    hn4[r] = hn;
                }
                uint2 p; p.x = pkbf(hn4[0], hn4[1]); p.y = pkbf(hn4[2], hn4[3]);
                hpk[nt] = p;
                *(uint2*)&hA[wro[nt]] = p;
            }
            wg_barrier();   // hA(t) visible for next pass 1 (lgkm-only)

            xz = nz; xr = nr; xg = ng;
        }

        // tail: Hout(TC-1), persist state, emit final hidden on last chunk
        {
            unsigned short* hp = Hout + (size_t)(TC - 1) * 8192 + holane;
            *(uint2*)hp        = hpk[0];
            *(uint2*)(hp + 16) = hpk[1];
        }
        #pragma unroll
        for (int nt = 0; nt < 2; ++nt) {
            int nb = wv * 32 + nt * 16 + qr * 4;
            float4 h4; h4.x = hreg[nt][0]; h4.y = hreg[nt][1]; h4.z = hreg[nt][2]; h4.w = hreg[nt][3];
            *(float4*)(hst + layer * 8192 + b * 256 + nb) = h4;
            if (last_chunk)
                *(float4*)(dout_tail + (size_t)b * 512 + layer * 256 + nb) = h4;
        }
        return;
    }

    // ======================= GEMM ROLE (512 thr, 128-row tile) =======================
    const int gb = bid - 4;
    const void* Aptr; int a_mode, c0abs = 0, o_mode, jtl, mtb;
    const float *w0, *w1, *w2, *b0, *b1, *b2; void* Optr;
    if (gb < 384) {
        int c = i + 1; if ((unsigned)c > 31u) return;
        a_mode = 0; Aptr = x; c0abs = c * TC;
        w0 = Wxz; w1 = Wxr; w2 = Wxg; b0 = bz; b1 = br; b2 = bg;
        Optr = XS0b + (size_t)(c & 1) * XSPAR; o_mode = 0; jtl = gb >> 5; mtb = gb & 31;
    } else if (gb < 768) {
        int c = i - 1; if ((unsigned)c > 31u) return;
        a_mode = 1; Aptr = Hc0b + (size_t)(c & 1) * HPAR;
        w0 = Wxz + LW; w1 = Wxr + LW; w2 = Wxg + LW;
        b0 = bz + 256; b1 = br + 256; b2 = bg + 256;
        Optr = XS1b + (size_t)(c & 1) * XSPAR; o_mode = 0; jtl = (gb - 384) >> 5; mtb = (gb - 384) & 31;
    } else {
        int c = i - 3; if ((unsigned)c > 31u) return;
        a_mode = 1; Aptr = Hc1b + (size_t)(c & 1) * HPAR; c0abs = c * TC;
        w0 = Why; w1 = Why; w2 = Why; b0 = by; b1 = by; b2 = by;
        Optr = out; o_mode = 1; jtl = (gb - 768) >> 5; mtb = (gb - 768) & 31;
    }

    unsigned short* Alds = sm.g.Alds;
    unsigned short* Wlds = sm.g.Wlds;

    // stage A: 128 rows x 256 k
    for (int idx = tid; idx < 8192; idx += 512) {
        int row = idx >> 6;
        int kq  = (idx & 63) << 2;
        int sw  = row * 256 + (((((kq >> 3) ^ (row & 7)) << 3)) | (kq & 7));
        if (a_mode == 0) {
            int i0 = mtb * 128 + row; int tc = i0 >> 5, bb = i0 & 31;
            const float* p = (const float*)Aptr + ((size_t)bb * SSZ + (size_t)(c0abs + tc)) * 256 + kq;
            float4 v = *(const float4*)p;
            ushort4 u; u.x = f2bf(v.x); u.y = f2bf(v.y); u.z = f2bf(v.z); u.w = f2bf(v.w);
            *(ushort4*)&Alds[sw] = u;
        } else {
            const unsigned short* p = (const unsigned short*)Aptr + (size_t)(mtb * 128 + row) * 256 + kq;
            *(ushort4*)&Alds[sw] = *(const ushort4*)p;
        }
    }
    // stage W: 64 rows x 256 k
    for (int idx = tid; idx < 4096; idx += 512) {
        int row = idx >> 6;
        int kq  = (idx & 63) << 2;
        int j   = jtl * 64 + row;
        const float* wp = (j < 256) ? w0 : ((j < 512) ? w1 : w2);
        const float* p  = wp + (size_t)(j & 255) * 256 + kq;
        float4 v = *(const float4*)p;
        ushort4 u; u.x = f2bf(v.x); u.y = f2bf(v.y); u.z = f2bf(v.z); u.w = f2bf(v.w);
        int sw = row * 256 + (((((kq >> 3) ^ (row & 7)) << 3)) | (kq & 7));
        *(ushort4*)&Wlds[sw] = u;
    }
    __syncthreads();

    const int lane = tid & 63, wv = tid >> 6;
    const int cl = lane & 15, qr = lane >> 4;
    const int sub = wv >> 2, wq = wv & 3;       // waves 0-3: rows 0-63; 4-7: rows 64-127
    f32x4 acc[4];
    #pragma unroll
    for (int nt = 0; nt < 4; ++nt) acc[nt] = (f32x4){0.f, 0.f, 0.f, 0.f};

    #pragma unroll
    for (int kt = 0; kt < 8; ++kt) {
        int kb = kt * 4 + qr;
        short8 af = *(const short8*)&Alds[(sub * 64 + wq * 16 + cl) * 256 + ((kb ^ (cl & 7)) << 3)];
        #pragma unroll
        for (int nt = 0; nt < 4; ++nt) {
            short8 bf = *(const short8*)&Wlds[(nt * 16 + cl) * 256 + ((kb ^ (cl & 7)) << 3)];
            acc[nt] = __builtin_amdgcn_mfma_f32_16x16x32_bf16(af, bf, acc[nt], 0, 0, 0);
        }
    }

    #pragma unroll
    for (int nt = 0; nt < 4; ++nt) {
        int j = jtl * 64 + nt * 16 + cl;
        const float* bp = (j < 256) ? b0 : ((j < 512) ? b1 : b2);
        float bias = bp[j & 255];
        #pragma unroll
        for (int r = 0; r < 4; ++r) {
            float v = acc[nt][r] + bias;
            int m = mtb * 128 + sub * 64 + wq * 16 + qr * 4 + r;
            if (o_mode == 0) {
                int t = m >> 5, bb = m & 31;
                int wgs = bb >> 4, scl = bb & 15;        // scan: sample -> lane cl
                int gate = j >> 8, cc = j & 255;
                // scan thread (8 waves): n = swv*32 + snt*16 + sqr*4 + sr
                int swv = cc >> 5, snt = (cc >> 4) & 1, sqr = (cc >> 2) & 3, sr = cc & 3;
                int stid = swv * 64 + sqr * 16 + scl;
                size_t off = (((size_t)((t * 2 + wgs) * 3 + gate)) << 12)
                           + (size_t)stid * 8 + (snt * 4 + sr);
                float gs = (gate < 2) ? SIGSC : TANHSC;
                ((unsigned short*)Optr)[off] = f2bf(v * gs);
            } else {
                int tc = m >> 5, bb = m & 31;
                ((float*)Optr)[(size_t)bb * (SSZ * 256) + (size_t)(c0abs + tc) * 256 + j] = v;
            }
        }
    }
}

extern "C" void kernel_launch(void* const* d_in, const int* in_sizes, int n_in,
                              void* d_out, int out_size, void* d_ws, size_t ws_size,
                              hipStream_t stream) {
    const float* x   = (const float*)d_in[0];
    const float* h0  = (const float*)d_in[1];
    const float* Wxz = (const float*)d_in[2];
    const float* Whz = (const float*)d_in[3];
    const float* bz  = (const float*)d_in[4];
    const float* Wxr = (const float*)d_in[5];
    const float* Whr = (const float*)d_in[6];
    const float* br  = (const float*)d_in[7];
    const float* Wxg = (const float*)d_in[8];
    const float* Whg = (const float*)d_in[9];
    const float* bg  = (const float*)d_in[10];
    const float* Why = (const float*)d_in[11];
    const float* by  = (const float*)d_in[12];
    float* out = (float*)d_out;

    char* ws = (char*)d_ws;                                          // same 33.6MB footprint
    unsigned short* bufA = (unsigned short*)(ws);                    // XS0: 2 parities x 6,291,456 B
    unsigned short* bufB = (unsigned short*)(ws + 12582912);         // XS1: 2 parities x 6,291,456 B
    unsigned short* Hc0  = (unsigned short*)(ws + 25165824);         // Hc0: 2 parities x 2,097,152 B
    unsigned short* Hc1  = (unsigned short*)(ws + 29360128);         // Hc1: 2 parities x 2,097,152 B
    float*          hst  = (float*)(ws + 33554432);                  // 65,536 B
    float* dout_tail = out + (size_t)32 * 4096 * 256;

    // pipeline: D(i) = scanL0(i) + scanL1(i-2) + gemmXS0(i+1) + gemmXS1(i-1)
    //           + gemmY(i-3); every dependency crosses a dispatch boundary.
    for (int i = -1; i <= 34; ++i) {
        fused<<<dim3(900), 512, 0, stream>>>(x, h0,
                                             Wxz, Whz, bz, Wxr, Whr, br,
                                             Wxg, Whg, bg, Why, by,
                                             bufA, bufB, Hc0, Hc1,
                                             hst, out, dout_tail, i);
    }
}